// Round 9
// baseline (35.100 us; speedup 1.0000x reference)
//
#include <hip/hip_runtime.h>

// ProSurv similarity loss, collapsed:
//   cm[b,c] = (h[b] . bankbar[c]) / max(||h[b]||, eps)
//   bankbar[c] = (1/M) sum_m bank[c,m] / max(||bank[c,m]||, eps)
// 3 dispatches, no memsets:
//   1) bank_kernel: 64 blocks, partials + last-block finalize (modulo counter:
//      poison-proof, replay-wraparound-safe since 64 | 2^32).
//   2) loss_kernel: 512 blocks x 256 thr; 8 threads per sample, ALL data
//      direct global->register (h chunks contiguous per thread; bankbar 8KB
//      L1-resident). No LDS staging, one sync, 30 shfl/wave.
//   3) final_kernel: 1 block sums lpart -> out[0] (single d_out store).

constexpr int NC = 4;     // classes
constexpr int NM = 512;   // prototypes per class
constexpr int ND = 256;   // feature dim
constexpr float EPSF = 1e-12f;

constexpr int ABLK = 64;                              // bank_kernel blocks (pow2)
constexpr int ROWS_PER_ABLK  = 2 * NC * NM / ABLK;    // 64
constexpr int ROWS_PER_AWAVE = ROWS_PER_ABLK / 4;     // 16
constexpr int PART_PER_COMBO = ABLK / (2 * NC);       // 8

constexpr int BBLK = 512;                             // loss blocks
constexpr int SPB  = 32;                              // samples per loss block

__device__ __forceinline__ float wave_reduce(float v) {
#pragma unroll
    for (int off = 32; off >= 1; off >>= 1)
        v += __shfl_xor(v, off, 64);
    return v;
}

// ---- Kernel 1: bank partials + last-block finalize -> bankbar ----
__global__ __launch_bounds__(256) void bank_kernel(
    const float* __restrict__ pbank, const float* __restrict__ gbank,
    float* __restrict__ partials, float* __restrict__ bankbar,
    unsigned int* __restrict__ counterA)
{
    const int blk  = blockIdx.x;
    const int wave = threadIdx.x >> 6;
    const int lane = threadIdx.x & 63;

    float4 acc = {0.f, 0.f, 0.f, 0.f};
    const int r0 = blk * ROWS_PER_ABLK + wave * ROWS_PER_AWAVE;
#pragma unroll
    for (int rr = 0; rr < ROWS_PER_AWAVE; ++rr) {
        const int r      = r0 + rr;
        const int bank   = r >> 11;
        const int within = r & (NC * NM - 1);
        const float* src = (bank ? gbank : pbank) + (size_t)within * ND;
        const float4 v = reinterpret_cast<const float4*>(src)[lane];
        float ss = v.x * v.x + v.y * v.y + v.z * v.z + v.w * v.w;
        ss = wave_reduce(ss);
        const float inv = 1.0f / (fmaxf(sqrtf(ss), EPSF) * (float)NM);
        acc.x += v.x * inv; acc.y += v.y * inv;
        acc.z += v.z * inv; acc.w += v.w * inv;
    }

    __shared__ float4 red[4][64];
    red[wave][lane] = acc;
    __syncthreads();
    if (wave == 0) {
        float4 a = red[0][lane], b = red[1][lane];
        float4 c = red[2][lane], d = red[3][lane];
        a.x += b.x + c.x + d.x; a.y += b.y + c.y + d.y;
        a.z += b.z + c.z + d.z; a.w += b.w + c.w + d.w;
        reinterpret_cast<float4*>(partials + (size_t)blk * ND)[lane] = a;
    }
    __syncthreads();

    __shared__ bool last;
    if (threadIdx.x == 0) {
        __threadfence();                              // release partials
        const unsigned int old = atomicAdd(counterA, 1u);
        last = ((old & (ABLK - 1)) == ABLK - 1);      // counter never reset
    }
    __syncthreads();

    if (last) {
        __threadfence();                              // acquire all partials
        const int c = threadIdx.x >> 5;               // combo 0..7
        const int j = threadIdx.x & 31;
#pragma unroll
        for (int k = 0; k < 2; ++k) {
            const int f4 = j + k * 32;
            float4 s = {0.f, 0.f, 0.f, 0.f};
#pragma unroll
            for (int p = 0; p < PART_PER_COMBO; ++p) {
                const float4 v = reinterpret_cast<const float4*>(
                    partials + (size_t)(c * PART_PER_COMBO + p) * ND)[f4];
                s.x += v.x; s.y += v.y; s.z += v.z; s.w += v.w;
            }
            reinterpret_cast<float4*>(bankbar + (size_t)c * ND)[f4] = s;
        }
    }
}

// ---- Kernel 2: loss, 8 threads/sample, all-register data path ----
__global__ __launch_bounds__(256) void loss_kernel(
    const float* __restrict__ hp, const float* __restrict__ hg,
    const int* __restrict__ label, const int* __restrict__ censor,
    const float* __restrict__ bankbar, float* __restrict__ lpart)
{
    const int t  = threadIdx.x;
    const int s  = t >> 3;                 // sample slot 0..31
    const int k  = t & 7;                  // 32-dim chunk 0..7
    const int sg = blockIdx.x * SPB + s;   // global sample

    const int  l   = label[sg];
    const bool evt = (censor[sg] == 0);

    // both modalities' chunks -> registers (16 independent 16B loads)
    const float4* hp4 = reinterpret_cast<const float4*>(hp + (size_t)sg * ND + k * 32);
    const float4* hg4 = reinterpret_cast<const float4*>(hg + (size_t)sg * ND + k * 32);
    float4 hx0[8], hx1[8];
#pragma unroll
    for (int j = 0; j < 8; ++j) hx0[j] = hp4[j];
#pragma unroll
    for (int j = 0; j < 8; ++j) hx1[j] = hg4[j];

    float s0[2], sc[2][NC];
#pragma unroll
    for (int md = 0; md < 2; ++md) {
        const float4* hx = md ? hx1 : hx0;

        float a0 = 0.f;
#pragma unroll
        for (int j = 0; j < 8; ++j)
            a0 += hx[j].x * hx[j].x + hx[j].y * hx[j].y
                + hx[j].z * hx[j].z + hx[j].w * hx[j].w;
        s0[md] = a0;

#pragma unroll
        for (int c = 0; c < NC; ++c) {
            const float4* bc = reinterpret_cast<const float4*>(
                bankbar + (size_t)(md * NC + c) * ND + k * 32);
            float acc = 0.f;
#pragma unroll
            for (int j = 0; j < 8; ++j) {
                const float4 w = bc[j];     // 8KB bankbar: L1-resident
                acc += hx[j].x * w.x + hx[j].y * w.y
                     + hx[j].z * w.z + hx[j].w * w.w;
            }
            sc[md][c] = acc;
        }
    }

    // 3-step butterfly over the 8-lane group, all 10 values
#pragma unroll
    for (int off = 1; off <= 4; off <<= 1) {
        s0[0] += __shfl_xor(s0[0], off, 64);
        s0[1] += __shfl_xor(s0[1], off, 64);
#pragma unroll
        for (int c = 0; c < NC; ++c) {
            sc[0][c] += __shfl_xor(sc[0][c], off, 64);
            sc[1][c] += __shfl_xor(sc[1][c], off, 64);
        }
    }

    // per-thread loss (group-replicated; only k==0 contributes)
    float contrib = 0.0f;
#pragma unroll
    for (int md = 0; md < 2; ++md) {
        const float inv = 1.0f / fmaxf(sqrtf(s0[md]), EPSF);
        float sum = 0.f, cml = 0.f, sge = 0.f, slt = 0.f;
#pragma unroll
        for (int c = 0; c < NC; ++c) {
            const float x = sc[md][c] * inv;
            sum += x;
            if (c == l) cml = x;
            if (c >= l) sge += x; else slt += x;
        }
        float pos, neg;
        if (evt) {
            pos = cml;
            neg = (sum - cml) * (1.0f / (NC - 1));
        } else {
            pos = sge / (float)(NC - l);          // l==0 -> pos_all
            neg = slt / (float)(l > 0 ? l : 1);   // l==0 -> 0
        }
        contrib += neg - pos;
    }
    if (k != 0) contrib = 0.0f;

    contrib = wave_reduce(contrib);
    __shared__ float wpart[4];
    if ((t & 63) == 0) wpart[t >> 6] = contrib;
    __syncthreads();
    if (t == 0)
        lpart[blockIdx.x] = wpart[0] + wpart[1] + wpart[2] + wpart[3];
}

// ---- Kernel 3: one block sums BBLK partials -> out[0] ----
__global__ __launch_bounds__(256) void final_kernel(
    const float* __restrict__ lpart, float* __restrict__ out)
{
    const int t = threadIdx.x;
    float v = lpart[t] + lpart[t + 256];
    v = wave_reduce(v);
    __shared__ float wp[4];
    if ((t & 63) == 0) wp[t >> 6] = v;
    __syncthreads();
    if (t == 0) out[0] = wp[0] + wp[1] + wp[2] + wp[3];
}

extern "C" void kernel_launch(void* const* d_in, const int* in_sizes, int n_in,
                              void* d_out, int out_size, void* d_ws, size_t ws_size,
                              hipStream_t stream)
{
    const float* hp     = (const float*)d_in[0];
    const float* hg     = (const float*)d_in[1];
    const float* pb     = (const float*)d_in[2];
    const float* gb     = (const float*)d_in[3];
    const int*   label  = (const int*)d_in[4];
    const int*   censor = (const int*)d_in[5];
    float*       out    = (float*)d_out;

    unsigned int* counterA = (unsigned int*)d_ws;             // never reset (modulo)
    float* partials = (float*)((char*)d_ws + 256);            // ABLK*ND = 64 KiB
    float* bankbar  = partials + (size_t)ABLK * ND;           // 8 KiB
    float* lpart    = bankbar + 2 * NC * ND;                  // BBLK floats

    bank_kernel <<<ABLK, 256, 0, stream>>>(pb, gb, partials, bankbar, counterA);
    loss_kernel <<<BBLK, 256, 0, stream>>>(hp, hg, label, censor, bankbar, lpart);
    final_kernel<<<1,    256, 0, stream>>>(lpart, out);
}

// Round 10
// 29.080 us; speedup vs baseline: 1.2070x; 1.2070x over previous
//
#include <hip/hip_runtime.h>

// ProSurv similarity loss, collapsed:
//   cm[b,c] = (h[b] . bankbar[c]) / max(||h[b]||, eps)
//   bankbar[c] = (1/M) sum_m bank[c,m] / max(||bank[c,m]||, eps)
// 3 dispatches, no memsets:
//   1) bank_kernel: 256 blocks, partials + last-block finalize (modulo
//      counter: poison-proof, wraparound-safe) -> bankbar in TRANSPOSED
//      layout bb_t[combo][j(8)][k(8)][4] (j = float4-within-chunk, k = chunk).
//   2) loss_kernel: 512 blocks x 256 thr; 8 threads/sample; h staged via
//      padded LDS (coalesced -> per-thread-contiguous); bank read as
//      broadcast 128B-line global loads (L1-resident, VMEM pipe).
//   3) final_kernel: 1 block sums lpart -> out[0] (single d_out store).

constexpr int NC = 4;     // classes
constexpr int NM = 512;   // prototypes per class
constexpr int ND = 256;   // feature dim
constexpr float EPSF = 1e-12f;

constexpr int ABLK = 256;                             // bank_kernel blocks (pow2)
constexpr int ROWS_PER_ABLK  = 2 * NC * NM / ABLK;    // 16
constexpr int ROWS_PER_AWAVE = ROWS_PER_ABLK / 4;     // 4
constexpr int PART_PER_COMBO = ABLK / (2 * NC);       // 32

constexpr int BBLK = 512;                             // loss blocks
constexpr int SPB  = 32;                              // samples per loss block
constexpr int CHW  = 36;                              // padded chunk width (32+4)
constexpr int SROW = 8 * CHW;                         // 288 floats per padded row

__device__ __forceinline__ float wave_reduce(float v) {
#pragma unroll
    for (int off = 32; off >= 1; off >>= 1)
        v += __shfl_xor(v, off, 64);
    return v;
}

// ---- Kernel 1: bank partials + last-block finalize -> transposed bankbar ----
__global__ __launch_bounds__(256) void bank_kernel(
    const float* __restrict__ pbank, const float* __restrict__ gbank,
    float* __restrict__ partials, float* __restrict__ bankbar_t,
    unsigned int* __restrict__ counterA)
{
    const int blk  = blockIdx.x;
    const int wave = threadIdx.x >> 6;
    const int lane = threadIdx.x & 63;

    float4 acc = {0.f, 0.f, 0.f, 0.f};
    const int r0 = blk * ROWS_PER_ABLK + wave * ROWS_PER_AWAVE;
#pragma unroll
    for (int rr = 0; rr < ROWS_PER_AWAVE; ++rr) {
        const int r      = r0 + rr;
        const int bank   = r >> 11;
        const int within = r & (NC * NM - 1);
        const float* src = (bank ? gbank : pbank) + (size_t)within * ND;
        const float4 v = reinterpret_cast<const float4*>(src)[lane];
        float ss = v.x * v.x + v.y * v.y + v.z * v.z + v.w * v.w;
        ss = wave_reduce(ss);
        const float inv = 1.0f / (fmaxf(sqrtf(ss), EPSF) * (float)NM);
        acc.x += v.x * inv; acc.y += v.y * inv;
        acc.z += v.z * inv; acc.w += v.w * inv;
    }

    __shared__ float4 red[4][64];
    red[wave][lane] = acc;
    __syncthreads();
    if (wave == 0) {
        float4 a = red[0][lane], b = red[1][lane];
        float4 c = red[2][lane], d = red[3][lane];
        a.x += b.x + c.x + d.x; a.y += b.y + c.y + d.y;
        a.z += b.z + c.z + d.z; a.w += b.w + c.w + d.w;
        reinterpret_cast<float4*>(partials + (size_t)blk * ND)[lane] = a;
    }
    __syncthreads();

    __shared__ bool last;
    if (threadIdx.x == 0) {
        __threadfence();                              // release partials
        const unsigned int old = atomicAdd(counterA, 1u);
        last = ((old & (ABLK - 1)) == ABLK - 1);      // counter never reset
    }
    __syncthreads();

    if (last) {
        __threadfence();                              // acquire all partials
        const int c  = threadIdx.x >> 5;              // combo 0..7
        const int jc = threadIdx.x & 31;
#pragma unroll
        for (int k2 = 0; k2 < 2; ++k2) {
            const int f4 = jc + k2 * 32;              // source float4 col 0..63
            float4 s = {0.f, 0.f, 0.f, 0.f};
#pragma unroll
            for (int p = 0; p < PART_PER_COMBO; ++p) {
                const float4 v = reinterpret_cast<const float4*>(
                    partials + (size_t)(c * PART_PER_COMBO + p) * ND)[f4];
                s.x += v.x; s.y += v.y; s.z += v.z; s.w += v.w;
            }
            // transpose: d = k*32 + j*4 + e  ->  slot j*8 + k
            const int k = f4 >> 3;
            const int j = f4 & 7;
            reinterpret_cast<float4*>(bankbar_t)[c * 64 + j * 8 + k] = s;
        }
    }
}

// ---- Kernel 2: loss, 8 threads/sample, LDS-staged h, broadcast bank ----
__global__ __launch_bounds__(256) void loss_kernel(
    const float* __restrict__ hp, const float* __restrict__ hg,
    const int* __restrict__ label, const int* __restrict__ censor,
    const float* __restrict__ bankbar_t, float* __restrict__ lpart)
{
    __shared__ __align__(16) float hbuf[SPB * SROW];   // 36 KiB, reused per modality

    const int t  = threadIdx.x;
    const int s  = t >> 3;                 // sample slot 0..31
    const int k  = t & 7;                  // 32-dim chunk 0..7
    const int sg = blockIdx.x * SPB + s;   // global sample

    const int  l   = label[sg];
    const bool evt = (censor[sg] == 0);

    const float4* bb4 = reinterpret_cast<const float4*>(bankbar_t);

    float s0[2], sc[2][NC];

#pragma unroll
    for (int md = 0; md < 2; ++md) {
        const float* src = (md ? hg : hp) + (size_t)blockIdx.x * SPB * ND;
        __syncthreads();   // protect hbuf from previous modality's readers
#pragma unroll
        for (int it = 0; it < 8; ++it) {
            const int f4  = t + it * 256;           // 0..2047
            const int ss  = f4 >> 6;                // sample slot
            const int rem = f4 & 63;
            const float4 v = reinterpret_cast<const float4*>(src)[f4];
            *reinterpret_cast<float4*>(&hbuf[ss * SROW + (rem >> 3) * CHW + (rem & 7) * 4]) = v;
        }
        __syncthreads();

        // per-thread: own 32-dim chunk of own sample from LDS
        const float* hrow = &hbuf[s * SROW + k * CHW];
        float4 hx[8];
#pragma unroll
        for (int j = 0; j < 8; ++j)
            hx[j] = reinterpret_cast<const float4*>(hrow)[j];

        float a0 = 0.f;
#pragma unroll
        for (int j = 0; j < 8; ++j)
            a0 += hx[j].x * hx[j].x + hx[j].y * hx[j].y
                + hx[j].z * hx[j].z + hx[j].w * hx[j].w;

        float ac[NC];
#pragma unroll
        for (int c = 0; c < NC; ++c) {
            const float4* bc = bb4 + (md * NC + c) * 64;   // transposed combo row
            float acc = 0.f;
#pragma unroll
            for (int j = 0; j < 8; ++j) {
                const float4 w = bc[j * 8 + k];   // lanes k=0..7: one 128B line, broadcast over s
                acc += hx[j].x * w.x + hx[j].y * w.y
                     + hx[j].z * w.z + hx[j].w * w.w;
            }
            ac[c] = acc;
        }

        // 3-step butterfly over the 8-lane group
#pragma unroll
        for (int off = 1; off <= 4; off <<= 1) {
            a0 += __shfl_xor(a0, off, 64);
#pragma unroll
            for (int c = 0; c < NC; ++c)
                ac[c] += __shfl_xor(ac[c], off, 64);
        }
        s0[md] = a0;
#pragma unroll
        for (int c = 0; c < NC; ++c) sc[md][c] = ac[c];
    }

    // per-thread loss (group-replicated; only k==0 contributes)
    float contrib = 0.0f;
#pragma unroll
    for (int md = 0; md < 2; ++md) {
        const float inv = 1.0f / fmaxf(sqrtf(s0[md]), EPSF);
        float sum = 0.f, cml = 0.f, sge = 0.f, slt = 0.f;
#pragma unroll
        for (int c = 0; c < NC; ++c) {
            const float x = sc[md][c] * inv;
            sum += x;
            if (c == l) cml = x;
            if (c >= l) sge += x; else slt += x;
        }
        float pos, neg;
        if (evt) {
            pos = cml;
            neg = (sum - cml) * (1.0f / (NC - 1));
        } else {
            pos = sge / (float)(NC - l);          // l==0 -> pos_all
            neg = slt / (float)(l > 0 ? l : 1);   // l==0 -> 0
        }
        contrib += neg - pos;
    }
    if (k != 0) contrib = 0.0f;

    contrib = wave_reduce(contrib);
    __shared__ float wpart[4];
    if ((t & 63) == 0) wpart[t >> 6] = contrib;
    __syncthreads();
    if (t == 0)
        lpart[blockIdx.x] = wpart[0] + wpart[1] + wpart[2] + wpart[3];
}

// ---- Kernel 3: one block sums BBLK partials -> out[0] ----
__global__ __launch_bounds__(256) void final_kernel(
    const float* __restrict__ lpart, float* __restrict__ out)
{
    const int t = threadIdx.x;
    float v = lpart[t] + lpart[t + 256];
    v = wave_reduce(v);
    __shared__ float wp[4];
    if ((t & 63) == 0) wp[t >> 6] = v;
    __syncthreads();
    if (t == 0) out[0] = wp[0] + wp[1] + wp[2] + wp[3];
}

extern "C" void kernel_launch(void* const* d_in, const int* in_sizes, int n_in,
                              void* d_out, int out_size, void* d_ws, size_t ws_size,
                              hipStream_t stream)
{
    const float* hp     = (const float*)d_in[0];
    const float* hg     = (const float*)d_in[1];
    const float* pb     = (const float*)d_in[2];
    const float* gb     = (const float*)d_in[3];
    const int*   label  = (const int*)d_in[4];
    const int*   censor = (const int*)d_in[5];
    float*       out    = (float*)d_out;

    unsigned int* counterA = (unsigned int*)d_ws;             // never reset (modulo)
    float* partials  = (float*)((char*)d_ws + 256);           // ABLK*ND = 256 KiB
    float* bankbar_t = partials + (size_t)ABLK * ND;          // 8 KiB (transposed)
    float* lpart     = bankbar_t + 2 * NC * ND;               // BBLK floats

    bank_kernel <<<ABLK, 256, 0, stream>>>(pb, gb, partials, bankbar_t, counterA);
    loss_kernel <<<BBLK, 256, 0, stream>>>(hp, hg, label, censor, bankbar_t, lpart);
    final_kernel<<<1,    256, 0, stream>>>(lpart, out);
}

// Round 11
// 28.137 us; speedup vs baseline: 1.2475x; 1.0335x over previous
//
#include <hip/hip_runtime.h>

// ProSurv similarity loss, collapsed:
//   cm[b,c] = (h[b] . bankbar[c]) / max(||h[b]||, eps)
//   bankbar[c] = (1/M) sum_m bank[c,m] / max(||bank[c,m]||, eps)
// 3 dispatches, no memsets:
//   1) bank_kernel: 256 blocks, partials + last-block finalize (modulo
//      counter: poison-proof, wraparound-safe since 256 | 2^32).
//   2) loss_kernel: 1024 blocks x 256 thr; 16 threads/sample; h and bank
//      staged in padded LDS (CHW=20, SROW=328: chunk starts 16B-aligned,
//      <=2-way bank aliasing which is free). Bank reads stay on LDS —
//      repeated d_ws reads proven slow (R10).
//   3) final_kernel: 1 block sums lpart -> out[0] (single d_out store).

constexpr int NC = 4;     // classes
constexpr int NM = 512;   // prototypes per class
constexpr int ND = 256;   // feature dim
constexpr float EPSF = 1e-12f;

constexpr int ABLK = 256;                             // bank_kernel blocks (pow2)
constexpr int ROWS_PER_ABLK  = 2 * NC * NM / ABLK;    // 16
constexpr int ROWS_PER_AWAVE = ROWS_PER_ABLK / 4;     // 4
constexpr int PART_PER_COMBO = ABLK / (2 * NC);       // 32

constexpr int BBLK = 1024;                            // loss blocks
constexpr int SPB  = 16;                              // samples per loss block
constexpr int CHW  = 20;                              // padded chunk width (16+4)
constexpr int SROW = 16 * CHW + 8;                    // 328: +8 spreads samples over quads

__device__ __forceinline__ float wave_reduce(float v) {
#pragma unroll
    for (int off = 32; off >= 1; off >>= 1)
        v += __shfl_xor(v, off, 64);
    return v;
}

// ---- Kernel 1: bank partials + last-block finalize -> bankbar ----
__global__ __launch_bounds__(256) void bank_kernel(
    const float* __restrict__ pbank, const float* __restrict__ gbank,
    float* __restrict__ partials, float* __restrict__ bankbar,
    unsigned int* __restrict__ counterA)
{
    const int blk  = blockIdx.x;
    const int wave = threadIdx.x >> 6;
    const int lane = threadIdx.x & 63;

    float4 acc = {0.f, 0.f, 0.f, 0.f};
    const int r0 = blk * ROWS_PER_ABLK + wave * ROWS_PER_AWAVE;
#pragma unroll
    for (int rr = 0; rr < ROWS_PER_AWAVE; ++rr) {
        const int r      = r0 + rr;
        const int bank   = r >> 11;
        const int within = r & (NC * NM - 1);
        const float* src = (bank ? gbank : pbank) + (size_t)within * ND;
        const float4 v = reinterpret_cast<const float4*>(src)[lane];
        float ss = v.x * v.x + v.y * v.y + v.z * v.z + v.w * v.w;
        ss = wave_reduce(ss);
        const float inv = 1.0f / (fmaxf(sqrtf(ss), EPSF) * (float)NM);
        acc.x += v.x * inv; acc.y += v.y * inv;
        acc.z += v.z * inv; acc.w += v.w * inv;
    }

    __shared__ float4 red[4][64];
    red[wave][lane] = acc;
    __syncthreads();
    if (wave == 0) {
        float4 a = red[0][lane], b = red[1][lane];
        float4 c = red[2][lane], d = red[3][lane];
        a.x += b.x + c.x + d.x; a.y += b.y + c.y + d.y;
        a.z += b.z + c.z + d.z; a.w += b.w + c.w + d.w;
        reinterpret_cast<float4*>(partials + (size_t)blk * ND)[lane] = a;
    }
    __syncthreads();

    __shared__ bool last;
    if (threadIdx.x == 0) {
        __threadfence();                              // release partials
        const unsigned int old = atomicAdd(counterA, 1u);
        last = ((old & (ABLK - 1)) == ABLK - 1);      // counter never reset
    }
    __syncthreads();

    if (last) {
        __threadfence();                              // acquire all partials
        const int c = threadIdx.x >> 5;               // combo 0..7
        const int j = threadIdx.x & 31;
#pragma unroll
        for (int k2 = 0; k2 < 2; ++k2) {
            const int f4 = j + k2 * 32;
            float4 s = {0.f, 0.f, 0.f, 0.f};
#pragma unroll
            for (int p = 0; p < PART_PER_COMBO; ++p) {
                const float4 v = reinterpret_cast<const float4*>(
                    partials + (size_t)(c * PART_PER_COMBO + p) * ND)[f4];
                s.x += v.x; s.y += v.y; s.z += v.z; s.w += v.w;
            }
            reinterpret_cast<float4*>(bankbar + (size_t)c * ND)[f4] = s;
        }
    }
}

// ---- Kernel 2: loss, 16 threads/sample, LDS-staged h and bank ----
__global__ __launch_bounds__(256) void loss_kernel(
    const float* __restrict__ hp, const float* __restrict__ hg,
    const int* __restrict__ label, const int* __restrict__ censor,
    const float* __restrict__ bankbar, float* __restrict__ lpart)
{
    __shared__ __align__(16) float hbuf[SPB * SROW];   // 16*328*4B = 20.5 KiB
    __shared__ __align__(16) float bb[8 * SROW];       // 10.3 KiB padded bankbar

    const int t  = threadIdx.x;
    const int s  = t >> 4;                 // sample slot 0..15
    const int k  = t & 15;                 // 16-dim chunk 0..15
    const int sg = blockIdx.x * SPB + s;   // global sample

    // stage padded bankbar: 512 float4s, 2 per thread
#pragma unroll
    for (int it = 0; it < 2; ++it) {
        const int f4    = t + it * 256;
        const int combo = f4 >> 6;
        const int rem   = f4 & 63;
        const float4 v  = reinterpret_cast<const float4*>(bankbar)[f4];
        *reinterpret_cast<float4*>(&bb[combo * SROW + (rem >> 2) * CHW + (rem & 3) * 4]) = v;
    }

    const int  l   = label[sg];
    const bool evt = (censor[sg] == 0);

    float s0[2], sc[2][NC];

#pragma unroll
    for (int md = 0; md < 2; ++md) {
        // stage 16 rows (16 KB) coalesced -> padded LDS
        const float* src = (md ? hg : hp) + (size_t)blockIdx.x * SPB * ND;
        __syncthreads();   // protect hbuf from previous modality's readers
#pragma unroll
        for (int it = 0; it < 4; ++it) {
            const int f4  = t + it * 256;           // 0..1023
            const int ss  = f4 >> 6;                // sample slot
            const int rem = f4 & 63;
            const float4 v = reinterpret_cast<const float4*>(src)[f4];
            *reinterpret_cast<float4*>(&hbuf[ss * SROW + (rem >> 2) * CHW + (rem & 3) * 4]) = v;
        }
        __syncthreads();

        // per-thread: own 16-dim chunk of own sample
        const float* hrow = &hbuf[s * SROW + k * CHW];
        float4 hx[4];
#pragma unroll
        for (int j = 0; j < 4; ++j)
            hx[j] = reinterpret_cast<const float4*>(hrow)[j];

        float a0 = 0.f;
#pragma unroll
        for (int j = 0; j < 4; ++j)
            a0 += hx[j].x * hx[j].x + hx[j].y * hx[j].y
                + hx[j].z * hx[j].z + hx[j].w * hx[j].w;

        float ac[NC];
#pragma unroll
        for (int c = 0; c < NC; ++c) {
            const float* brow = &bb[(md * NC + c) * SROW + k * CHW];
            float acc = 0.f;
#pragma unroll
            for (int j = 0; j < 4; ++j) {
                const float4 w = reinterpret_cast<const float4*>(brow)[j];
                acc += hx[j].x * w.x + hx[j].y * w.y
                     + hx[j].z * w.z + hx[j].w * w.w;
            }
            ac[c] = acc;
        }

        // 4-step butterfly over the 16-lane group (all lanes get totals)
#pragma unroll
        for (int off = 1; off <= 8; off <<= 1) {
            a0 += __shfl_xor(a0, off, 64);
#pragma unroll
            for (int c = 0; c < NC; ++c)
                ac[c] += __shfl_xor(ac[c], off, 64);
        }
        s0[md] = a0;
#pragma unroll
        for (int c = 0; c < NC; ++c) sc[md][c] = ac[c];
    }

    // per-thread loss (group-replicated; only k==0 contributes)
    float contrib = 0.0f;
#pragma unroll
    for (int md = 0; md < 2; ++md) {
        const float inv = 1.0f / fmaxf(sqrtf(s0[md]), EPSF);
        float sum = 0.f, cml = 0.f, sge = 0.f, slt = 0.f;
#pragma unroll
        for (int c = 0; c < NC; ++c) {
            const float x = sc[md][c] * inv;
            sum += x;
            if (c == l) cml = x;
            if (c >= l) sge += x; else slt += x;
        }
        float pos, neg;
        if (evt) {
            pos = cml;
            neg = (sum - cml) * (1.0f / (NC - 1));
        } else {
            pos = sge / (float)(NC - l);          // l==0 -> pos_all
            neg = slt / (float)(l > 0 ? l : 1);   // l==0 -> 0
        }
        contrib += neg - pos;
    }
    if (k != 0) contrib = 0.0f;

    contrib = wave_reduce(contrib);
    __shared__ float wpart[4];
    if ((t & 63) == 0) wpart[t >> 6] = contrib;
    __syncthreads();
    if (t == 0)
        lpart[blockIdx.x] = wpart[0] + wpart[1] + wpart[2] + wpart[3];
}

// ---- Kernel 3: one block sums BBLK partials -> out[0] ----
__global__ __launch_bounds__(256) void final_kernel(
    const float* __restrict__ lpart, float* __restrict__ out)
{
    const int t = threadIdx.x;
    float v = 0.f;
#pragma unroll
    for (int q = 0; q < BBLK / 256; ++q)
        v += lpart[t + q * 256];
    v = wave_reduce(v);
    __shared__ float wp[4];
    if ((t & 63) == 0) wp[t >> 6] = v;
    __syncthreads();
    if (t == 0) out[0] = wp[0] + wp[1] + wp[2] + wp[3];
}

extern "C" void kernel_launch(void* const* d_in, const int* in_sizes, int n_in,
                              void* d_out, int out_size, void* d_ws, size_t ws_size,
                              hipStream_t stream)
{
    const float* hp     = (const float*)d_in[0];
    const float* hg     = (const float*)d_in[1];
    const float* pb     = (const float*)d_in[2];
    const float* gb     = (const float*)d_in[3];
    const int*   label  = (const int*)d_in[4];
    const int*   censor = (const int*)d_in[5];
    float*       out    = (float*)d_out;

    unsigned int* counterA = (unsigned int*)d_ws;             // never reset (modulo)
    float* partials = (float*)((char*)d_ws + 256);            // ABLK*ND = 256 KiB
    float* bankbar  = partials + (size_t)ABLK * ND;           // 8 KiB
    float* lpart    = bankbar + 2 * NC * ND;                  // BBLK floats

    bank_kernel <<<ABLK, 256, 0, stream>>>(pb, gb, partials, bankbar, counterA);
    loss_kernel <<<BBLK, 256, 0, stream>>>(hp, hg, label, censor, bankbar, lpart);
    final_kernel<<<1,    256, 0, stream>>>(lpart, out);
}

// Round 12
// 22.603 us; speedup vs baseline: 1.5529x; 1.2448x over previous
//
#include <hip/hip_runtime.h>

// ProSurv similarity loss, collapsed:
//   cm[b,c] = (h[b] . bankbar[c]) / max(||h[b]||, eps)
//   bankbar[c] = (1/M) sum_m bank[c,m] / max(||bank[c,m]||, eps)
// 3 dispatches, no memsets:
//   1) bank_kernel: 64 blocks (fences only at this tiny grid — proven cheap;
//      256+ blocks proven to cost ~7us, R10/R11), modulo counter finalize.
//   2) loss_kernel: 512 blocks x 256 thr; 8 threads/sample; SINGLE staging
//      phase (bb + both modalities, 18 loads/thread in flight), ONE sync,
//      compute both modalities, per-wave lpart store. 80KB LDS = 2 blk/CU.
//   3) final_kernel: 1 block sums 2048 lpart -> out[0] (single d_out store).

constexpr int NC = 4;     // classes
constexpr int NM = 512;   // prototypes per class
constexpr int ND = 256;   // feature dim
constexpr float EPSF = 1e-12f;

constexpr int ABLK = 64;                              // bank_kernel blocks (pow2)
constexpr int ROWS_PER_ABLK  = 2 * NC * NM / ABLK;    // 64
constexpr int ROWS_PER_AWAVE = ROWS_PER_ABLK / 4;     // 16
constexpr int PART_PER_COMBO = ABLK / (2 * NC);       // 8

constexpr int BBLK = 512;                             // loss blocks
constexpr int SPB  = 32;                              // samples per loss block
constexpr int CHW  = 36;                              // padded chunk width (32+4)
constexpr int SROW = 8 * CHW;                         // 288 floats per padded row
constexpr int HMD  = SPB * SROW;                      // 9216 floats per modality

__device__ __forceinline__ float wave_reduce(float v) {
#pragma unroll
    for (int off = 32; off >= 1; off >>= 1)
        v += __shfl_xor(v, off, 64);
    return v;
}

// ---- Kernel 1: bank partials + last-block finalize -> bankbar ----
__global__ __launch_bounds__(256) void bank_kernel(
    const float* __restrict__ pbank, const float* __restrict__ gbank,
    float* __restrict__ partials, float* __restrict__ bankbar,
    unsigned int* __restrict__ counterA)
{
    const int blk  = blockIdx.x;
    const int wave = threadIdx.x >> 6;
    const int lane = threadIdx.x & 63;

    float4 acc = {0.f, 0.f, 0.f, 0.f};
    const int r0 = blk * ROWS_PER_ABLK + wave * ROWS_PER_AWAVE;
#pragma unroll
    for (int rr = 0; rr < ROWS_PER_AWAVE; ++rr) {
        const int r      = r0 + rr;
        const int bank   = r >> 11;
        const int within = r & (NC * NM - 1);
        const float* src = (bank ? gbank : pbank) + (size_t)within * ND;
        const float4 v = reinterpret_cast<const float4*>(src)[lane];
        float ss = v.x * v.x + v.y * v.y + v.z * v.z + v.w * v.w;
        ss = wave_reduce(ss);
        const float inv = 1.0f / (fmaxf(sqrtf(ss), EPSF) * (float)NM);
        acc.x += v.x * inv; acc.y += v.y * inv;
        acc.z += v.z * inv; acc.w += v.w * inv;
    }

    __shared__ float4 red[4][64];
    red[wave][lane] = acc;
    __syncthreads();
    if (wave == 0) {
        float4 a = red[0][lane], b = red[1][lane];
        float4 c = red[2][lane], d = red[3][lane];
        a.x += b.x + c.x + d.x; a.y += b.y + c.y + d.y;
        a.z += b.z + c.z + d.z; a.w += b.w + c.w + d.w;
        reinterpret_cast<float4*>(partials + (size_t)blk * ND)[lane] = a;
    }
    __syncthreads();

    __shared__ bool last;
    if (threadIdx.x == 0) {
        __threadfence();                              // release partials
        const unsigned int old = atomicAdd(counterA, 1u);
        last = ((old & (ABLK - 1)) == ABLK - 1);      // counter never reset
    }
    __syncthreads();

    if (last) {
        __threadfence();                              // acquire all partials
        const int c = threadIdx.x >> 5;               // combo 0..7
        const int j = threadIdx.x & 31;
#pragma unroll
        for (int k2 = 0; k2 < 2; ++k2) {
            const int f4 = j + k2 * 32;
            float4 s = {0.f, 0.f, 0.f, 0.f};
#pragma unroll
            for (int p = 0; p < PART_PER_COMBO; ++p) {
                const float4 v = reinterpret_cast<const float4*>(
                    partials + (size_t)(c * PART_PER_COMBO + p) * ND)[f4];
                s.x += v.x; s.y += v.y; s.z += v.z; s.w += v.w;
            }
            reinterpret_cast<float4*>(bankbar + (size_t)c * ND)[f4] = s;
        }
    }
}

// ---- Kernel 2: loss, 8 thr/sample, single-phase staging, one sync ----
__global__ __launch_bounds__(256) void loss_kernel(
    const float* __restrict__ hp, const float* __restrict__ hg,
    const int* __restrict__ label, const int* __restrict__ censor,
    const float* __restrict__ bankbar, float* __restrict__ lpart)
{
    __shared__ __align__(16) float hbuf[2 * HMD];      // 72 KiB (both modalities)
    __shared__ __align__(16) float bb[2 * NC * ND];    // 8 KiB linear bankbar

    const int t  = threadIdx.x;
    const int s  = t >> 3;                 // sample slot 0..31
    const int k  = t & 7;                  // 32-dim chunk 0..7
    const int sg = blockIdx.x * SPB + s;   // global sample

    // ---- single staging burst: bb (2) + hp (8) + hg (8) loads in flight ----
    reinterpret_cast<float4*>(bb)[t]       = reinterpret_cast<const float4*>(bankbar)[t];
    reinterpret_cast<float4*>(bb)[t + 256] = reinterpret_cast<const float4*>(bankbar)[t + 256];

    const float* srcp = hp + (size_t)blockIdx.x * SPB * ND;
    const float* srcg = hg + (size_t)blockIdx.x * SPB * ND;
#pragma unroll
    for (int it = 0; it < 8; ++it) {
        const int f4  = t + it * 256;           // 0..2047
        const int ss  = f4 >> 6;
        const int rem = f4 & 63;
        const int dst = ss * SROW + (rem >> 3) * CHW + (rem & 7) * 4;
        *reinterpret_cast<float4*>(&hbuf[dst])       = reinterpret_cast<const float4*>(srcp)[f4];
        *reinterpret_cast<float4*>(&hbuf[HMD + dst]) = reinterpret_cast<const float4*>(srcg)[f4];
    }

    const int  l   = label[sg];
    const bool evt = (censor[sg] == 0);

    __syncthreads();   // the only barrier before the store

    float contrib = 0.0f;
#pragma unroll
    for (int md = 0; md < 2; ++md) {
        const float* hrow = &hbuf[md * HMD + s * SROW + k * CHW];
        float4 hx[8];
#pragma unroll
        for (int j = 0; j < 8; ++j)
            hx[j] = reinterpret_cast<const float4*>(hrow)[j];

        float a0 = 0.f;
#pragma unroll
        for (int j = 0; j < 8; ++j)
            a0 += hx[j].x * hx[j].x + hx[j].y * hx[j].y
                + hx[j].z * hx[j].z + hx[j].w * hx[j].w;

        float ac[NC];
#pragma unroll
        for (int c = 0; c < NC; ++c) {
            const float* brow = &bb[(md * NC + c) * ND + k * 32];
            float acc = 0.f;
#pragma unroll
            for (int j = 0; j < 8; ++j) {
                const float4 w = reinterpret_cast<const float4*>(brow)[j];
                acc += hx[j].x * w.x + hx[j].y * w.y
                     + hx[j].z * w.z + hx[j].w * w.w;
            }
            ac[c] = acc;
        }

        // 3-step butterfly over the 8-lane group (all lanes get totals)
#pragma unroll
        for (int off = 1; off <= 4; off <<= 1) {
            a0 += __shfl_xor(a0, off, 64);
#pragma unroll
            for (int c = 0; c < NC; ++c)
                ac[c] += __shfl_xor(ac[c], off, 64);
        }

        const float inv = 1.0f / fmaxf(sqrtf(a0), EPSF);
        float sum = 0.f, cml = 0.f, sge = 0.f, slt = 0.f;
#pragma unroll
        for (int c = 0; c < NC; ++c) {
            const float x = ac[c] * inv;
            sum += x;
            if (c == l) cml = x;
            if (c >= l) sge += x; else slt += x;
        }
        float pos, neg;
        if (evt) {
            pos = cml;
            neg = (sum - cml) * (1.0f / (NC - 1));
        } else {
            pos = sge / (float)(NC - l);          // l==0 -> pos_all
            neg = slt / (float)(l > 0 ? l : 1);   // l==0 -> 0
        }
        contrib += neg - pos;
    }
    if (k != 0) contrib = 0.0f;

    contrib = wave_reduce(contrib);
    if ((t & 63) == 0)
        lpart[(blockIdx.x << 2) | (t >> 6)] = contrib;   // per-wave store, no syncs
}

// ---- Kernel 3: one block sums 4*BBLK partials -> out[0] ----
__global__ __launch_bounds__(256) void final_kernel(
    const float* __restrict__ lpart, float* __restrict__ out)
{
    const int t = threadIdx.x;
    float v = 0.f;
#pragma unroll
    for (int q = 0; q < 4 * BBLK / 256; ++q)
        v += lpart[t + q * 256];
    v = wave_reduce(v);
    __shared__ float wp[4];
    if ((t & 63) == 0) wp[t >> 6] = v;
    __syncthreads();
    if (t == 0) out[0] = wp[0] + wp[1] + wp[2] + wp[3];
}

extern "C" void kernel_launch(void* const* d_in, const int* in_sizes, int n_in,
                              void* d_out, int out_size, void* d_ws, size_t ws_size,
                              hipStream_t stream)
{
    const float* hp     = (const float*)d_in[0];
    const float* hg     = (const float*)d_in[1];
    const float* pb     = (const float*)d_in[2];
    const float* gb     = (const float*)d_in[3];
    const int*   label  = (const int*)d_in[4];
    const int*   censor = (const int*)d_in[5];
    float*       out    = (float*)d_out;

    unsigned int* counterA = (unsigned int*)d_ws;             // never reset (modulo)
    float* partials = (float*)((char*)d_ws + 256);            // ABLK*ND = 64 KiB
    float* bankbar  = partials + (size_t)ABLK * ND;           // 8 KiB
    float* lpart    = bankbar + 2 * NC * ND;                  // 4*BBLK floats

    bank_kernel <<<ABLK, 256, 0, stream>>>(pb, gb, partials, bankbar, counterA);
    loss_kernel <<<BBLK, 256, 0, stream>>>(hp, hg, label, censor, bankbar, lpart);
    final_kernel<<<1,    256, 0, stream>>>(lpart, out);
}

// Round 14
// 19.636 us; speedup vs baseline: 1.7875x; 1.1511x over previous
//
#include <hip/hip_runtime.h>

// ProSurv similarity loss, collapsed:
//   cm[b,c] = (h[b] . bankbar[c]) / max(||h[b]||, eps)
//   bankbar[c] = (1/M) sum_m bank[c,m] / max(||bank[c,m]||, eps)
// 3 dispatches, no memsets, NO cross-block synchronization of any kind:
//   1) bank_partial_kernel: 64 blocks write 64 partial vectors (plain stores).
//   2) loss_kernel: 512 blocks; staging phase sums the 8 partials/combo
//      in-block (visibility via dispatch boundary — race-free by design;
//      R13 proved last-block fence handoff loses cross-XCD races), then
//      8 threads/sample LDS compute (R8 structure, proven fastest).
//   3) final_kernel: 1 block sums lpart -> out[0] (single d_out store).

constexpr int NC = 4;     // classes
constexpr int NM = 512;   // prototypes per class
constexpr int ND = 256;   // feature dim
constexpr float EPSF = 1e-12f;

constexpr int ABLK = 64;                              // bank partial blocks
constexpr int ROWS_PER_ABLK  = 2 * NC * NM / ABLK;    // 64
constexpr int ROWS_PER_AWAVE = ROWS_PER_ABLK / 4;     // 16
constexpr int PART_PER_COMBO = ABLK / (2 * NC);       // 8

constexpr int BBLK = 512;                             // loss blocks
constexpr int SPB  = 32;                              // samples per loss block
constexpr int CHW  = 36;                              // padded chunk width (32+4)
constexpr int SROW = 8 * CHW;                         // 288 floats per padded row

__device__ __forceinline__ float wave_reduce(float v) {
#pragma unroll
    for (int off = 32; off >= 1; off >>= 1)
        v += __shfl_xor(v, off, 64);
    return v;
}

// ---- Kernel 1: normalized-row partial sums (pure writer, no sync) ----
__global__ __launch_bounds__(256) void bank_partial_kernel(
    const float* __restrict__ pbank, const float* __restrict__ gbank,
    float* __restrict__ partials)
{
    const int blk  = blockIdx.x;
    const int wave = threadIdx.x >> 6;
    const int lane = threadIdx.x & 63;

    float4 acc = {0.f, 0.f, 0.f, 0.f};
    const int r0 = blk * ROWS_PER_ABLK + wave * ROWS_PER_AWAVE;
#pragma unroll
    for (int rr = 0; rr < ROWS_PER_AWAVE; ++rr) {
        const int r      = r0 + rr;
        const int bank   = r >> 11;
        const int within = r & (NC * NM - 1);
        const float* src = (bank ? gbank : pbank) + (size_t)within * ND;
        const float4 v = reinterpret_cast<const float4*>(src)[lane];
        float ss = v.x * v.x + v.y * v.y + v.z * v.z + v.w * v.w;
        ss = wave_reduce(ss);
        const float inv = 1.0f / (fmaxf(sqrtf(ss), EPSF) * (float)NM);
        acc.x += v.x * inv; acc.y += v.y * inv;
        acc.z += v.z * inv; acc.w += v.w * inv;
    }

    __shared__ float4 red[4][64];
    red[wave][lane] = acc;
    __syncthreads();
    if (wave == 0) {
        float4 a = red[0][lane], b = red[1][lane];
        float4 c = red[2][lane], d = red[3][lane];
        a.x += b.x + c.x + d.x; a.y += b.y + c.y + d.y;
        a.z += b.z + c.z + d.z; a.w += b.w + c.w + d.w;
        reinterpret_cast<float4*>(partials + (size_t)blk * ND)[lane] = a;
    }
}

// ---- Kernel 2: loss; in-block bankbar reduce + 8 thr/sample compute ----
__global__ __launch_bounds__(256) void loss_kernel(
    const float* __restrict__ hp, const float* __restrict__ hg,
    const int* __restrict__ label, const int* __restrict__ censor,
    const float* __restrict__ partials, float* __restrict__ lpart)
{
    __shared__ __align__(16) float hbuf[SPB * SROW];   // 36 KiB, reused per modality
    __shared__ __align__(16) float bb[8 * SROW];       // 9 KiB padded bankbar

    const int t = threadIdx.x;
    const int s = t >> 3;          // sample slot 0..31
    const int k = t & 7;           // dim-chunk 0..7 (32 dims each)
    const int sg = blockIdx.x * SPB + s;     // global sample

    // build padded bankbar in-block: 512 float4 columns, 2 per thread;
    // each = sum of this combo's 8 partials (64KB broadcast, L2/IF$-hot)
    const float4* p4 = reinterpret_cast<const float4*>(partials);
#pragma unroll
    for (int it = 0; it < 2; ++it) {
        const int f4    = t + it * 256;       // 0..511
        const int combo = f4 >> 6;
        const int rem   = f4 & 63;
        float4 sv = {0.f, 0.f, 0.f, 0.f};
#pragma unroll
        for (int p = 0; p < PART_PER_COMBO; ++p) {
            const float4 v = p4[(size_t)(combo * PART_PER_COMBO + p) * 64 + rem];
            sv.x += v.x; sv.y += v.y; sv.z += v.z; sv.w += v.w;
        }
        *reinterpret_cast<float4*>(&bb[combo * SROW + (rem >> 3) * CHW + (rem & 7) * 4]) = sv;
    }

    const int l   = label[sg];
    const bool evt = (censor[sg] == 0);

    float s0[2], sc[2][NC];

#pragma unroll
    for (int md = 0; md < 2; ++md) {
        // stage 32 rows (32 KB) coalesced -> padded LDS
        const float* src = (md ? hg : hp) + (size_t)blockIdx.x * SPB * ND;
        __syncthreads();   // protect hbuf from previous modality's readers
#pragma unroll
        for (int it = 0; it < 8; ++it) {
            const int f4  = t + it * 256;           // 0..2047
            const int ss  = f4 >> 6;                // sample slot
            const int rem = f4 & 63;
            const float4 v = reinterpret_cast<const float4*>(src)[f4];
            *reinterpret_cast<float4*>(&hbuf[ss * SROW + (rem >> 3) * CHW + (rem & 7) * 4]) = v;
        }
        __syncthreads();

        // per-thread: own 32-dim chunk of own sample
        const float* hrow = &hbuf[s * SROW + k * CHW];
        float4 hx[8];
#pragma unroll
        for (int j = 0; j < 8; ++j)
            hx[j] = reinterpret_cast<const float4*>(hrow)[j];

        float a0 = 0.f;
#pragma unroll
        for (int j = 0; j < 8; ++j)
            a0 += hx[j].x * hx[j].x + hx[j].y * hx[j].y
                + hx[j].z * hx[j].z + hx[j].w * hx[j].w;

        float ac[NC];
#pragma unroll
        for (int c = 0; c < NC; ++c) {
            const float* brow = &bb[(md * NC + c) * SROW + k * CHW];
            float acc = 0.f;
#pragma unroll
            for (int j = 0; j < 8; ++j) {
                const float4 w = reinterpret_cast<const float4*>(brow)[j];
                acc += hx[j].x * w.x + hx[j].y * w.y
                     + hx[j].z * w.z + hx[j].w * w.w;
            }
            ac[c] = acc;
        }

        // 3-step butterfly over the 8-lane group (all lanes get totals)
#pragma unroll
        for (int off = 1; off <= 4; off <<= 1) {
            a0 += __shfl_xor(a0, off, 64);
#pragma unroll
            for (int c = 0; c < NC; ++c)
                ac[c] += __shfl_xor(ac[c], off, 64);
        }
        s0[md] = a0;
#pragma unroll
        for (int c = 0; c < NC; ++c) sc[md][c] = ac[c];
    }

    // per-thread loss (group-replicated; only k==0 contributes)
    float contrib = 0.0f;
#pragma unroll
    for (int md = 0; md < 2; ++md) {
        const float inv = 1.0f / fmaxf(sqrtf(s0[md]), EPSF);
        float sum = 0.f, cml = 0.f, sge = 0.f, slt = 0.f;
#pragma unroll
        for (int c = 0; c < NC; ++c) {
            const float x = sc[md][c] * inv;
            sum += x;
            if (c == l) cml = x;
            if (c >= l) sge += x; else slt += x;
        }
        float pos, neg;
        if (evt) {
            pos = cml;
            neg = (sum - cml) * (1.0f / (NC - 1));
        } else {
            pos = sge / (float)(NC - l);          // l==0 -> pos_all
            neg = slt / (float)(l > 0 ? l : 1);   // l==0 -> 0
        }
        contrib += neg - pos;
    }
    if (k != 0) contrib = 0.0f;

    // block reduction -> lpart
    contrib = wave_reduce(contrib);
    __shared__ float wpart[4];
    if ((t & 63) == 0) wpart[t >> 6] = contrib;
    __syncthreads();
    if (t == 0)
        lpart[blockIdx.x] = wpart[0] + wpart[1] + wpart[2] + wpart[3];
}

// ---- Kernel 3: one block sums BBLK partials -> out[0] ----
__global__ __launch_bounds__(256) void final_kernel(
    const float* __restrict__ lpart, float* __restrict__ out)
{
    const int t = threadIdx.x;
    float v = lpart[t] + lpart[t + 256];
    v = wave_reduce(v);
    __shared__ float wp[4];
    if ((t & 63) == 0) wp[t >> 6] = v;
    __syncthreads();
    if (t == 0) out[0] = wp[0] + wp[1] + wp[2] + wp[3];
}

extern "C" void kernel_launch(void* const* d_in, const int* in_sizes, int n_in,
                              void* d_out, int out_size, void* d_ws, size_t ws_size,
                              hipStream_t stream)
{
    const float* hp     = (const float*)d_in[0];
    const float* hg     = (const float*)d_in[1];
    const float* pb     = (const float*)d_in[2];
    const float* gb     = (const float*)d_in[3];
    const int*   label  = (const int*)d_in[4];
    const int*   censor = (const int*)d_in[5];
    float*       out    = (float*)d_out;

    float* partials = (float*)d_ws;                           // ABLK*ND = 64 KiB
    float* lpart    = partials + (size_t)ABLK * ND;           // BBLK floats

    bank_partial_kernel<<<ABLK, 256, 0, stream>>>(pb, gb, partials);
    loss_kernel        <<<BBLK, 256, 0, stream>>>(hp, hg, label, censor,
                                                  partials, lpart);
    final_kernel       <<<1,    256, 0, stream>>>(lpart, out);
}